// Round 14
// baseline (73.163 us; speedup 1.0000x reference)
//
#include <hip/hip_runtime.h>

// Problem constants
#define DL 16384   // D*L tokens
#define LL 2048
#define NQB 64     // NQ
#define QBS 32     // QB
#define KBS 128    // KB

typedef __attribute__((ext_vector_type(8))) short short8;
typedef __attribute__((ext_vector_type(4))) short short4v;
typedef __attribute__((ext_vector_type(4))) float f32x4;

__device__ __forceinline__ float sigmoidf_(float x) { return 1.f / (1.f + expf(-x)); }

__device__ __forceinline__ short f2bf(float f) {
    union { float f; unsigned u; } v; v.f = f;
    unsigned r = (v.u + 0x7FFFu + ((v.u >> 16) & 1u)) >> 16;
    return (short)r;
}
__device__ __forceinline__ float bf2f(short h) {
    union { unsigned u; float f; } v; v.u = ((unsigned)(unsigned short)h) << 16;
    return v.f;
}
__device__ __forceinline__ unsigned packbf16(short a, short b) {
    return ((unsigned)(unsigned short)a) | (((unsigned)(unsigned short)b) << 16);
}

// fragment helpers (cl = lane&15, kg = lane>>4 must be in scope)
#define AFRAG(buf, stride, r0, kk) (*(const short8*)&(buf)[(size_t)((r0) + cl) * (stride) + (kk) * 32 + kg * 8])
#define WFRAG(Wt, K, n0, kk) (*(const short8*)((Wt) + (size_t)((n0) + cl) * (K) + (kk) * 32 + kg * 8))
#define MFMA(acc, a, b) acc = __builtin_amdgcn_mfma_f32_16x16x32_bf16(a, b, acc, 0, 0, 0)

// ---------------------------------------------------------------------------
// Kernel 0: transpose of the 6 weights Phase-B needs.  6 blocks.
// ---------------------------------------------------------------------------
__global__ __launch_bounds__(256) void k_wtrans(
    const float* __restrict__ W0, const float* __restrict__ W1, const float* __restrict__ W2,
    const float* __restrict__ W3, const float* __restrict__ W4, const float* __restrict__ W5,
    short* __restrict__ wout)
{
    __shared__ float sW[128 * 128];          // 64 KB
    const int b = blockIdx.x;
    const int tid = threadIdx.x;
    const float* srcs[6] = {W0,W1,W2,W3,W4,W5};
    const float* src = srcs[b];
    short* dst = wout + b * 16384;
    {   // coalesced load of 128x128 f32 tile
        const int r = tid >> 1, ch = (tid & 1) * 64;
        #pragma unroll
        for (int u = 0; u < 16; ++u) {
            float4 v = *(const float4*)(src + (size_t)r * 128 + ch + u * 4);
            *(float4*)&sW[r * 128 + ch + u * 4] = v;
        }
    }
    __syncthreads();
    {   // coalesced transposed bf16 write
        const int o = tid >> 1, kh = (tid & 1) * 64;
        #pragma unroll
        for (int u8 = 0; u8 < 8; ++u8) {
            short8 pk;
            #pragma unroll
            for (int e = 0; e < 8; ++e)
                pk[e] = f2bf(sW[(kh + u8 * 8 + e) * 128 + o]);
            *(short8*)(dst + (size_t)o * 128 + kh + u8 * 8) = pk;
        }
    }
}

// ---------------------------------------------------------------------------
// Kernel 1: blocks 0..511   : adaLN1 + QKV+G (32 tokens each)
//           blocks 512..1023: pair-bias BBt[n][h][q:32][key:128]
//           blocks 1024..1034: transpose of the 11 attn/post-only weights
// ---------------------------------------------------------------------------
__global__ __launch_bounds__(512) void k_main(
    const float* __restrict__ A_I, const float* __restrict__ S_I,
    const short* __restrict__ Wg1t, const short* __restrict__ Ws1t,
    const short* __restrict__ Wqt, const short* __restrict__ Wkt,
    const short* __restrict__ Wvt, const short* __restrict__ Wgat,
    const float* __restrict__ bg1, const float* __restrict__ bq,
    const float* __restrict__ Z, const float* __restrict__ g16, const float* __restrict__ b16,
    const float* __restrict__ Wb,
    const float* __restrict__ Wa, const float* __restrict__ Wop, const float* __restrict__ ctWg,
    const float* __restrict__ a2Wg, const float* __restrict__ a2Ws,
    const float* __restrict__ Wsw, const float* __restrict__ Wlin, const float* __restrict__ Wout2,
    short* __restrict__ Qo, short* __restrict__ Ko, short* __restrict__ Vo, short* __restrict__ Go,
    short* __restrict__ BBt, short* __restrict__ wbt)
{
    __shared__ __align__(16) char smem[65536];
    const int bid = blockIdx.x;
    const int tid = threadIdx.x;
    const int lane = tid & 63;

    if (bid >= 1024) {
        // ------------- transpose path: 11 blocks, matrices 6..16 -------------
        float* sW = (float*)smem;
        const int b = bid - 1024;        // 0..10
        const float* srcs[8] = {Wa,Wop,ctWg,a2Wg,a2Ws,Wsw,Wlin,Wout2};
        const int sel[11]  = {0,1,2,3,4,5,5,6,6,7,7};
        const int soff[11] = {0,0,0,0,0, 0,128, 0,128, 0,16384};
        const int sN[11]   = {128,128,128,128,128, 256,256,256,256, 128,128};
        const int doff[11] = {98304,114688,131072,147456,163840,
                              180224,196608, 212992,229376, 245760,245888};
        const int dK[11]   = {128,128,128,128,128, 128,128,128,128, 256,256};
        const float* src = srcs[sel[b]] + soff[b];
        const int srcN = sN[b];
        short* dst = wbt + doff[b];
        const int dstK = dK[b];
        {   // coalesced load (512 threads, 32 f32 each)
            const int r = tid >> 2, ch = (tid & 3) * 32;
            #pragma unroll
            for (int u = 0; u < 8; ++u) {
                float4 v = *(const float4*)(src + (size_t)r * srcN + ch + u * 4);
                *(float4*)&sW[r * 128 + ch + u * 4] = v;
            }
        }
        __syncthreads();
        {   // coalesced transposed bf16 write
            const int o = tid >> 2, kh = (tid & 3) * 32;
            #pragma unroll
            for (int u8 = 0; u8 < 4; ++u8) {
                short8 pk;
                #pragma unroll
                for (int e = 0; e < 8; ++e)
                    pk[e] = f2bf(sW[(kh + u8 * 8 + e) * 128 + o]);
                *(short8*)(dst + (size_t)o * dstK + kh + u8 * 8) = pk;
            }
        }
        return;
    }

    if (bid >= 512) {
        // ---------------- bias path: one 4-row slice of one n ----------------
        float* sWb = (float*)smem;                 // [64]
        float* sg  = (float*)(smem + 256);         // [16]
        float* sb  = (float*)(smem + 320);         // [16]
        short* sT  = (short*)(smem + 384);         // [4][4][128]
        const int bb = bid - 512;        // 0..511
        const int n = bb >> 3;           // 0..63
        const int io = (bb & 7) * 4;     // 4-row slice
        if (tid < 64) sWb[tid] = Wb[tid];
        if (tid < 16) { sg[tid] = g16[tid]; sb[tid] = b16[tid]; }
        __syncthreads();
        {
            int il = tid >> 7, j = tid & 127;   // 512 threads = 4*128 pairs
            int i = io + il;
            int kr = n * 32 - 48 + j;
            int kc = min(max(kr, 0), LL - 1);
            const float4* z4 = (const float4*)(Z + ((long)(n * 32 + i) * LL + kc) * 16);
            float zv[16];
            #pragma unroll
            for (int w = 0; w < 4; ++w) {
                float4 v = z4[w];
                zv[w * 4 + 0] = v.x; zv[w * 4 + 1] = v.y; zv[w * 4 + 2] = v.z; zv[w * 4 + 3] = v.w;
            }
            float sm = 0.f, sq = 0.f;
            #pragma unroll
            for (int cp = 0; cp < 16; ++cp) { sm += zv[cp]; sq = fmaf(zv[cp], zv[cp], sq); }
            float m = sm * (1.f / 16.f);
            float rs = rsqrtf(sq * (1.f / 16.f) - m * m + 1e-5f);
            float b0 = 0.f, b1 = 0.f, b2 = 0.f, b3 = 0.f;
            #pragma unroll
            for (int cp = 0; cp < 16; ++cp) {
                float zn = (zv[cp] - m) * rs * sg[cp] + sb[cp];
                b0 = fmaf(zn, sWb[cp * 4 + 0], b0);
                b1 = fmaf(zn, sWb[cp * 4 + 1], b1);
                b2 = fmaf(zn, sWb[cp * 4 + 2], b2);
                b3 = fmaf(zn, sWb[cp * 4 + 3], b3);
            }
            sT[(0 * 4 + il) * 128 + j] = f2bf(b0);
            sT[(1 * 4 + il) * 128 + j] = f2bf(b1);
            sT[(2 * 4 + il) * 128 + j] = f2bf(b2);
            sT[(3 * 4 + il) * 128 + j] = f2bf(b3);
        }
        __syncthreads();
        {   // write BBt[n][h][q=io+il][key jb..jb+3]
            int hh = tid >> 7, rem = tid & 127;
            int il = rem >> 5, jb = (rem & 31) * 4;
            short4v pk = *(const short4v*)&sT[(hh * 4 + il) * 128 + jb];
            *(short4v*)(BBt + (((size_t)n * 4 + hh) * 32 + io + il) * 128 + jb) = pk;
        }
        return;
    }

    // ---------------- adaLN1 + QKVG path ----------------
    short* sAr = (short*)smem;               // [32][136]
    short* sSn = (short*)(smem + 8704);      // [32][136]
    short* sAn = (short*)(smem + 17408);     // [32][136]
    float* sMean = (float*)(smem + 26112);   // [32]
    float* sRstd = (float*)(smem + 26240);   // [32]
    const long t0 = (long)bid * 32;
    {   // P0
        const int row = tid >> 4, seg = tid & 15;
        const float* ap = A_I + (t0 + row) * 128 + seg * 8;
        const float* sp = S_I + (t0 + row) * 128 + seg * 8;
        float av[8], sv[8];
        #pragma unroll
        for (int u = 0; u < 2; ++u) {
            float4 a4 = ((const float4*)ap)[u];
            float4 s4 = ((const float4*)sp)[u];
            av[4*u] = a4.x; av[4*u+1] = a4.y; av[4*u+2] = a4.z; av[4*u+3] = a4.w;
            sv[4*u] = s4.x; sv[4*u+1] = s4.y; sv[4*u+2] = s4.z; sv[4*u+3] = s4.w;
        }
        float am = 0.f, aq = 0.f, sm = 0.f, sq = 0.f;
        #pragma unroll
        for (int u = 0; u < 8; ++u) {
            am += av[u]; aq = fmaf(av[u], av[u], aq);
            sm += sv[u]; sq = fmaf(sv[u], sv[u], sq);
        }
        am += __shfl_xor(am, 1); am += __shfl_xor(am, 2); am += __shfl_xor(am, 4); am += __shfl_xor(am, 8);
        aq += __shfl_xor(aq, 1); aq += __shfl_xor(aq, 2); aq += __shfl_xor(aq, 4); aq += __shfl_xor(aq, 8);
        sm += __shfl_xor(sm, 1); sm += __shfl_xor(sm, 2); sm += __shfl_xor(sm, 4); sm += __shfl_xor(sm, 8);
        sq += __shfl_xor(sq, 1); sq += __shfl_xor(sq, 2); sq += __shfl_xor(sq, 4); sq += __shfl_xor(sq, 8);
        float amean = am * (1.f / 128.f);
        float arstd = rsqrtf(aq * (1.f / 128.f) - amean * amean + 1e-5f);
        float smean = sm * (1.f / 128.f);
        float srstd = rsqrtf(sq * (1.f / 128.f) - smean * smean + 1e-5f);
        if ((tid & 15) == 0) { sMean[row] = amean; sRstd[row] = arstd; }
        short8 pa, ps;
        #pragma unroll
        for (int e = 0; e < 8; ++e) {
            pa[e] = f2bf(av[e]);
            ps[e] = f2bf((sv[e] - smean) * srstd);
        }
        *(short8*)&sAr[row * 136 + seg * 8] = pa;
        *(short8*)&sSn[row * 136 + seg * 8] = ps;
    }
    __syncthreads();
    const int w = tid >> 6;
    const int n0 = w * 16;
    const int cl = lane & 15, kg = lane >> 4;
    {   // P1: An = sigmoid(sn@Wg1+bg1)*an + sn@Ws1  [swapped]
        short8 wg[4], wsf[4];
        #pragma unroll
        for (int kk = 0; kk < 4; ++kk) {
            wg[kk]  = WFRAG(Wg1t, 128, n0, kk);
            wsf[kk] = WFRAG(Ws1t, 128, n0, kk);
        }
        #pragma unroll
        for (int mt = 0; mt < 2; ++mt) {
            f32x4 ag = {0.f, 0.f, 0.f, 0.f}, as = {0.f, 0.f, 0.f, 0.f};
            #pragma unroll
            for (int kk = 0; kk < 4; ++kk) {
                short8 a = AFRAG(sSn, 136, mt * 16, kk);
                MFMA(ag, wg[kk], a);
                MFMA(as, wsf[kk], a);
            }
            const int tok = mt * 16 + cl;
            const int c0 = n0 + kg * 4;
            float4 bg4 = *(const float4*)&bg1[c0];
            float mean = sMean[tok], rstd = sRstd[tok];
            short4v ar4 = *(const short4v*)&sAr[tok * 136 + c0];
            short4v o;
            #pragma unroll
            for (int i = 0; i < 4; ++i) {
                float an = (bf2f(ar4[i]) - mean) * rstd;
                float An = sigmoidf_(ag[i] + ((const float*)&bg4)[i]) * an + as[i];
                o[i] = f2bf(An);
            }
            *(short4v*)&sAn[tok * 136 + c0] = o;
        }
    }
    __syncthreads();
    {   // P2: Q,K,V,G  [swapped, 8B stores]
        const float SCL = 0.17677669529663687f;  // 1/sqrt(32)
        short8 af[2][4];
        #pragma unroll
        for (int mt = 0; mt < 2; ++mt)
            #pragma unroll
            for (int kk = 0; kk < 4; ++kk)
                af[mt][kk] = AFRAG(sAn, 136, mt * 16, kk);
        const int c0 = n0 + kg * 4;
        float4 bq4 = *(const float4*)&bq[c0];
        #pragma unroll
        for (int m = 0; m < 4; ++m) {
            const short* Wt = (m == 0) ? Wqt : (m == 1) ? Wkt : (m == 2) ? Wvt : Wgat;
            short8 wf[4];
            #pragma unroll
            for (int kk = 0; kk < 4; ++kk) wf[kk] = WFRAG(Wt, 128, n0, kk);
            #pragma unroll
            for (int mt = 0; mt < 2; ++mt) {
                f32x4 acc = {0.f, 0.f, 0.f, 0.f};
                #pragma unroll
                for (int kk = 0; kk < 4; ++kk) MFMA(acc, wf[kk], af[mt][kk]);
                long t = t0 + mt * 16 + cl;
                short4v o;
                if (m == 0) {
                    #pragma unroll
                    for (int i = 0; i < 4; ++i) o[i] = f2bf((acc[i] + ((const float*)&bq4)[i]) * SCL);
                    *(short4v*)(Qo + t * 128 + c0) = o;
                } else if (m == 1) {
                    #pragma unroll
                    for (int i = 0; i < 4; ++i) o[i] = f2bf(acc[i]);
                    *(short4v*)(Ko + t * 128 + c0) = o;
                } else if (m == 2) {
                    #pragma unroll
                    for (int i = 0; i < 4; ++i) o[i] = f2bf(acc[i]);
                    *(short4v*)(Vo + t * 128 + c0) = o;
                } else {
                    #pragma unroll
                    for (int i = 0; i < 4; ++i) o[i] = f2bf(sigmoidf_(acc[i]));
                    *(short4v*)(Go + t * 128 + c0) = o;
                }
            }
        }
    }
}

// ---------------------------------------------------------------------------
// Kernel 2: FUSED attention + post.  1-D grid 512, d = p&7 (XCD-local d-slice),
// n = p>>3: each XCD's L2 holds its d's full K/V (1 MB) -> window re-reads hit L2.
// A_I/S_I/G loads hoisted before PV barrier (T14).
// ---------------------------------------------------------------------------
__global__ __launch_bounds__(512) void k_attn_postf(
    const short* __restrict__ Qg, const short* __restrict__ Kg, const short* __restrict__ Vg,
    const short* __restrict__ Gg, const short* __restrict__ BBt, const float* __restrict__ maskK,
    const float* __restrict__ S_I, const float* __restrict__ A_I,
    const short* __restrict__ Wat, const short* __restrict__ Wopt, const short* __restrict__ ctWgt,
    const short* __restrict__ Wg2t, const short* __restrict__ Ws2t,
    const short* __restrict__ Wswt, const short* __restrict__ Wlint, const short* __restrict__ Wout2t,
    const float* __restrict__ bop, const float* __restrict__ ctbg, const float* __restrict__ bg2,
    float* __restrict__ Out)
{
    __shared__ __align__(16) char smem[78336];
    short* sAF  = (short*)smem;              // [32][136] attn-out bf16 -> later an2
    short* vts  = (short*)(smem + 8704);     // [4][32][136] V^T   (attn phase)
    short* Pl   = (short*)(smem + 43520);    // [4][32][136] P     (attn phase)
    // post phase (overlays vts/Pl after barrier):
    short* sS   = (short*)(smem + 8704);     // [32][136] raw S bf16 -> sB
    short* sSn  = (short*)(smem + 17408);    // [32][136] LN(S) bf16
    float* sA   = (float*)(smem + 26112);    // [32][132] f32 A
    float* sMean = (float*)(smem + 43008);   // [32]
    float* sRstd = (float*)(smem + 43136);   // [32]
    short* sAn2 = sAF;
    short* sB   = (short*)(smem + 8704);     // [32][264] bf16 b

    const int p = blockIdx.x;
    const int n = p >> 3, d = p & 7;         // XCD (p%8) owns one d-slice
    const int tid = threadIdx.x;
    const int lane = tid & 63;
    const long tb = (long)d * LL;
    const long t0 = tb + n * 32;
    const int kbase = n * 32 - 48;
    const int cl = lane & 15, kg = lane >> 4;
    const int w = tid >> 6;
    const int h = w >> 1, amt = w & 1;       // attn wave = (head, q-half)

    {   // V^T staging: 512 threads; unit=(head,key-pair), half=16-channel half
        const int unit = tid >> 1, half = tid & 1;
        const int hh = unit >> 6, j0 = (unit & 63) * 2;
        int kc0 = min(max(kbase + j0, 0), LL - 1);
        int kc1 = min(max(kbase + j0 + 1, 0), LL - 1);
        const short8* p0 = (const short8*)(Vg + (tb + kc0) * 128 + hh * 32 + half * 16);
        const short8* p1 = (const short8*)(Vg + (tb + kc1) * 128 + hh * 32 + half * 16);
        short8 e0 = p0[0], e1 = p0[1];
        short8 o0 = p1[0], o1 = p1[1];
        short* vh = vts + hh * 4352;
        #pragma unroll
        for (int e = 0; e < 8; ++e)
            *(unsigned*)&vh[(half * 16 + e) * 136 + j0] = packbf16(e0[e], o0[e]);
        #pragma unroll
        for (int e = 0; e < 8; ++e)
            *(unsigned*)&vh[(half * 16 + 8 + e) * 136 + j0] = packbf16(e1[e], o1[e]);
    }

    float sc[8][4];
    {   // swapped QK^T: lane -> token = amt*16+cl, keys nt*16+kg*4+i
        short8 qf = *(const short8*)(Qg + (t0 + amt * 16 + cl) * 128 + h * 32 + kg * 8);
        #pragma unroll
        for (int nt = 0; nt < 8; ++nt) {
            int kc = min(max(kbase + nt * 16 + cl, 0), LL - 1);
            short8 kf = *(const short8*)(Kg + (tb + kc) * 128 + h * 32 + kg * 8);
            f32x4 s = {0.f, 0.f, 0.f, 0.f};
            MFMA(s, kf, qf);       // A=K rows (m=key), B=Q rows (n=token)
            float4 mk4 = *(const float4*)(maskK + n * 128 + nt * 16 + kg * 4);
            short4v bfr = *(const short4v*)(BBt + (((size_t)n * 4 + h) * 32 + amt * 16 + cl) * 128 + nt * 16 + kg * 4);
            #pragma unroll
            for (int i = 0; i < 4; ++i)
                sc[nt][i] = s[i] + bf2f(bfr[i]) - ((const float*)&mk4)[i] * 1e9f;
        }
    }
    {   // softmax per token (lane holds 32 keys; reduce across 4 kg groups)
        float mx = sc[0][0];
        #pragma unroll
        for (int nt = 0; nt < 8; ++nt)
            #pragma unroll
            for (int i = 0; i < 4; ++i) mx = fmaxf(mx, sc[nt][i]);
        mx = fmaxf(mx, __shfl_xor(mx, 16));
        mx = fmaxf(mx, __shfl_xor(mx, 32));
        float sm = 0.f;
        #pragma unroll
        for (int nt = 0; nt < 8; ++nt)
            #pragma unroll
            for (int i = 0; i < 4; ++i) {
                float pe = __expf(sc[nt][i] - mx);
                sc[nt][i] = pe; sm += pe;
            }
        sm += __shfl_xor(sm, 16);
        sm += __shfl_xor(sm, 32);
        float inv = 1.f / sm;
        short* PH = Pl + h * 4352;
        const int tok = amt * 16 + cl;
        #pragma unroll
        for (int nt = 0; nt < 8; ++nt) {
            short4v p4;
            #pragma unroll
            for (int i = 0; i < 4; ++i) p4[i] = f2bf(sc[nt][i] * inv);
            *(short4v*)&PH[tok * 136 + nt * 16 + kg * 4] = p4;
        }
    }

    // T14: issue next-phase global loads NOW (registers) so HBM latency hides
    // under the PV MFMA phase after the barrier.
    const int prow = tid >> 4, pseg = tid & 15;
    float pav[8], psv[8];
    {
        const float* apI = A_I + (t0 + prow) * 128 + pseg * 8;
        const float* spI = S_I + (t0 + prow) * 128 + pseg * 8;
        #pragma unroll
        for (int u = 0; u < 2; ++u) {
            float4 a4 = ((const float4*)apI)[u];
            float4 s4 = ((const float4*)spI)[u];
            pav[4*u] = a4.x; pav[4*u+1] = a4.y; pav[4*u+2] = a4.z; pav[4*u+3] = a4.w;
            psv[4*u] = s4.x; psv[4*u+1] = s4.y; psv[4*u+2] = s4.z; psv[4*u+3] = s4.w;
        }
    }
    short4v g4h[2];
    {
        const int tok = amt * 16 + cl;
        #pragma unroll
        for (int ct = 0; ct < 2; ++ct)
            g4h[ct] = *(const short4v*)(Gg + (t0 + tok) * 128 + h * 32 + ct * 16 + kg * 4);
    }

    __syncthreads();   // V^T + P complete
    {   // PV + G-gate -> sAF (LDS), swapped: C col=token, rows=channels
        short* PH = Pl + h * 4352;
        short* vh = vts + h * 4352;
        const int tok = amt * 16 + cl;
        short8 pfr[4];
        #pragma unroll
        for (int kk = 0; kk < 4; ++kk)
            pfr[kk] = *(const short8*)&PH[tok * 136 + kk * 32 + kg * 8];
        #pragma unroll
        for (int ct = 0; ct < 2; ++ct) {
            f32x4 acc = {0.f, 0.f, 0.f, 0.f};
            #pragma unroll
            for (int kk = 0; kk < 4; ++kk) {
                short8 a = *(const short8*)&vh[(ct * 16 + cl) * 136 + kk * 32 + kg * 8];
                MFMA(acc, a, pfr[kk]);
            }
            const int c0 = h * 32 + ct * 16 + kg * 4;
            short4v o4;
            #pragma unroll
            for (int i = 0; i < 4; ++i) o4[i] = f2bf(bf2f(g4h[ct][i]) * acc[i]);
            *(short4v*)&sAF[tok * 136 + c0] = o4;
        }
    }
    __syncthreads();   // attn done; vts/Pl now dead

    // ---------------- post phase ----------------
    {   // P0: LN stats from pre-loaded registers; write sA/sS/sSn
        #pragma unroll
        for (int u = 0; u < 2; ++u)
            *(float4*)&sA[prow * 132 + pseg * 8 + u * 4] = *(const float4*)&pav[u * 4];
        float sm = 0.f, sq = 0.f;
        #pragma unroll
        for (int u = 0; u < 8; ++u) { sm += psv[u]; sq = fmaf(psv[u], psv[u], sq); }
        sm += __shfl_xor(sm, 1); sm += __shfl_xor(sm, 2); sm += __shfl_xor(sm, 4); sm += __shfl_xor(sm, 8);
        sq += __shfl_xor(sq, 1); sq += __shfl_xor(sq, 2); sq += __shfl_xor(sq, 4); sq += __shfl_xor(sq, 8);
        float smean = sm * (1.f / 128.f);
        float srstd = rsqrtf(sq * (1.f / 128.f) - smean * smean + 1e-5f);
        short8 pr, pn;
        #pragma unroll
        for (int e = 0; e < 8; ++e) {
            float s = psv[e];
            pr[e] = f2bf(s);
            pn[e] = f2bf((s - smean) * srstd);
        }
        *(short8*)&sS [prow * 136 + pseg * 8] = pr;
        *(short8*)&sSn[prow * 136 + pseg * 8] = pn;
    }
    __syncthreads();
    const int n0 = w * 16;
    const int c0 = n0 + kg * 4;
    float g2s[8];

    {   // P2: A = A_I + sigmoid(S@Wop+bop)*(AF@Wa);  g2 = sigmoid(S@ctWg+ctbg)
        short8 wA[4], wO[4], wG[4];
        #pragma unroll
        for (int kk = 0; kk < 4; ++kk) {
            wA[kk] = WFRAG(Wat, 128, n0, kk);
            wO[kk] = WFRAG(Wopt, 128, n0, kk);
            wG[kk] = WFRAG(ctWgt, 128, n0, kk);
        }
        float4 bop4 = *(const float4*)&bop[c0];
        float4 ct4  = *(const float4*)&ctbg[c0];
        #pragma unroll
        for (int rt = 0; rt < 2; ++rt) {
            f32x4 aA = {0.f,0.f,0.f,0.f}, aO = {0.f,0.f,0.f,0.f}, aG = {0.f,0.f,0.f,0.f};
            #pragma unroll
            for (int kk = 0; kk < 4; ++kk) {
                short8 af = AFRAG(sAF, 136, rt * 16, kk);
                short8 sf = AFRAG(sS, 136, rt * 16, kk);
                MFMA(aA, wA[kk], af);
                MFMA(aO, wO[kk], sf);
                MFMA(aG, wG[kk], sf);
            }
            const int tok = rt * 16 + cl;
            float4 Av = *(const float4*)&sA[tok * 132 + c0];
            float4 outv;
            #pragma unroll
            for (int i = 0; i < 4; ++i) {
                ((float*)&outv)[i] = ((const float*)&Av)[i]
                    + sigmoidf_(aO[i] + ((const float*)&bop4)[i]) * aA[i];
                g2s[rt * 4 + i] = sigmoidf_(aG[i] + ((const float*)&ct4)[i]);
            }
            *(float4*)&sA[tok * 132 + c0] = outv;
        }
    }
    __syncthreads();
    {   // P3: LN stats of A rows
        float m = 0.f, q = 0.f;
        #pragma unroll
        for (int u = 0; u < 2; ++u) {
            float4 v = *(const float4*)&sA[prow * 132 + pseg * 8 + u * 4];
            m += v.x + v.y + v.z + v.w;
            q = fmaf(v.x, v.x, q); q = fmaf(v.y, v.y, q);
            q = fmaf(v.z, v.z, q); q = fmaf(v.w, v.w, q);
        }
        m += __shfl_xor(m, 1); m += __shfl_xor(m, 2); m += __shfl_xor(m, 4); m += __shfl_xor(m, 8);
        q += __shfl_xor(q, 1); q += __shfl_xor(q, 2); q += __shfl_xor(q, 4); q += __shfl_xor(q, 8);
        float mean = m * (1.f / 128.f);
        float rstd = rsqrtf(q * (1.f / 128.f) - mean * mean + 1e-5f);
        if ((tid & 15) == 0) { sMean[prow] = mean; sRstd[prow] = rstd; }
    }
    __syncthreads();
    {   // P4: an2 = sigmoid(sn@Wg2+bg2)*LN(A) + sn@Ws2  (writes sAn2 = sAF)
        short8 wg2[4], ws2[4];
        #pragma unroll
        for (int kk = 0; kk < 4; ++kk) {
            wg2[kk] = WFRAG(Wg2t, 128, n0, kk);
            ws2[kk] = WFRAG(Ws2t, 128, n0, kk);
        }
        float4 bg24 = *(const float4*)&bg2[c0];
        #pragma unroll
        for (int rt = 0; rt < 2; ++rt) {
            f32x4 ag = {0.f,0.f,0.f,0.f}, as = {0.f,0.f,0.f,0.f};
            #pragma unroll
            for (int kk = 0; kk < 4; ++kk) {
                short8 a = AFRAG(sSn, 136, rt * 16, kk);
                MFMA(ag, wg2[kk], a);
                MFMA(as, ws2[kk], a);
            }
            const int tok = rt * 16 + cl;
            float mean = sMean[tok], rstd = sRstd[tok];
            float4 Av = *(const float4*)&sA[tok * 132 + c0];
            short4v o;
            #pragma unroll
            for (int i = 0; i < 4; ++i) {
                float lnA = (((const float*)&Av)[i] - mean) * rstd;
                o[i] = f2bf(sigmoidf_(ag[i] + ((const float*)&bg24)[i]) * lnA + as[i]);
            }
            *(short4v*)&sAn2[tok * 136 + c0] = o;
        }
    }
    __syncthreads();
    {   // P5: b = silu(an2@Wsw) * (an2@Wlin)  (writes sB over sS/sSn)
        short8 a2f[2][4];
        #pragma unroll
        for (int rt = 0; rt < 2; ++rt)
            #pragma unroll
            for (int kk = 0; kk < 4; ++kk)
                a2f[rt][kk] = AFRAG(sAn2, 136, rt * 16, kk);
        #pragma unroll
        for (int j = 0; j < 2; ++j) {
            const int n0b = w * 32 + j * 16;
            short8 ww[4], wl[4];
            #pragma unroll
            for (int kk = 0; kk < 4; ++kk) {
                ww[kk] = WFRAG(Wswt, 128, n0b, kk);
                wl[kk] = WFRAG(Wlint, 128, n0b, kk);
            }
            #pragma unroll
            for (int rt = 0; rt < 2; ++rt) {
                f32x4 aw = {0.f,0.f,0.f,0.f}, al = {0.f,0.f,0.f,0.f};
                #pragma unroll
                for (int kk = 0; kk < 4; ++kk) {
                    MFMA(aw, ww[kk], a2f[rt][kk]);
                    MFMA(al, wl[kk], a2f[rt][kk]);
                }
                const int tok = rt * 16 + cl;
                short4v o;
                #pragma unroll
                for (int i = 0; i < 4; ++i) {
                    float x = aw[i];
                    o[i] = f2bf((x / (1.f + expf(-x))) * al[i]);
                }
                *(short4v*)&sB[tok * 264 + n0b + kg * 4] = o;
            }
        }
    }
    __syncthreads();
    {   // P6: out = A + g2 * (b @ Wout2)  [float4 stores]
        short8 wo[8];
        #pragma unroll
        for (int kk = 0; kk < 8; ++kk) wo[kk] = WFRAG(Wout2t, 256, n0, kk);
        #pragma unroll
        for (int rt = 0; rt < 2; ++rt) {
            f32x4 acc = {0.f,0.f,0.f,0.f};
            #pragma unroll
            for (int kk = 0; kk < 8; ++kk) {
                short8 a = AFRAG(sB, 264, rt * 16, kk);
                MFMA(acc, wo[kk], a);
            }
            const int tok = rt * 16 + cl;
            float4 Av = *(const float4*)&sA[tok * 132 + c0];
            float4 outv;
            #pragma unroll
            for (int i = 0; i < 4; ++i)
                ((float*)&outv)[i] = ((const float*)&Av)[i] + g2s[rt * 4 + i] * acc[i];
            *(float4*)(Out + (t0 + tok) * 128 + c0) = outv;
        }
    }
}

// ---------------------------------------------------------------------------
extern "C" void kernel_launch(void* const* d_in, const int* in_sizes, int n_in,
                              void* d_out, int out_size, void* d_ws, size_t ws_size,
                              hipStream_t stream)
{
    const float* A_I  = (const float*)d_in[0];
    const float* S_I  = (const float*)d_in[1];
    const float* Z    = (const float*)d_in[2];
    const float* maskK = (const float*)d_in[6];
    const float* a1Wg = (const float*)d_in[7];
    const float* a1bg = (const float*)d_in[8];
    const float* a1Ws = (const float*)d_in[9];
    const float* Wq   = (const float*)d_in[10];
    const float* bq   = (const float*)d_in[11];
    const float* Wk   = (const float*)d_in[12];
    const float* Wv   = (const float*)d_in[13];
    const float* ln0g = (const float*)d_in[14];
    const float* ln0b = (const float*)d_in[15];
    const float* Wb   = (const float*)d_in[16];
    const float* Wga  = (const float*)d_in[17];
    const float* Wa   = (const float*)d_in[18];
    const float* Wop  = (const float*)d_in[19];
    const float* bop  = (const float*)d_in[20];
    const float* a2Wg = (const float*)d_in[21];
    const float* a2bg = (const float*)d_in[22];
    const float* a2Ws = (const float*)d_in[23];
    const float* Wsw  = (const float*)d_in[24];
    const float* Wlin = (const float*)d_in[25];
    const float* ctWg = (const float*)d_in[26];
    const float* ctbg = (const float*)d_in[27];
    const float* Wout2 = (const float*)d_in[28];
    float* out = (float*)d_out;

    const size_t NTC = (size_t)DL * 128;   // 2,097,152 elems per (D,L,C) tensor
    short* Qb = (short*)d_ws;
    short* Kb = Qb + NTC;
    short* Vb = Kb + NTC;
    short* Gb = Vb + NTC;
    short* BBt = Gb + NTC;                 // [64][4][32][128] bf16 = 2 MB
    short* wbt = BBt + (size_t)NQB * 4 * 32 * 128;

    short* Wg1t = wbt + 0 * 16384;
    short* Ws1t = wbt + 1 * 16384;
    short* Wqt  = wbt + 2 * 16384;
    short* Wkt  = wbt + 3 * 16384;
    short* Wvt  = wbt + 4 * 16384;
    short* Wgat = wbt + 5 * 16384;
    short* Wat  = wbt + 6 * 16384;
    short* Wopt = wbt + 7 * 16384;
    short* ctWgt = wbt + 8 * 16384;
    short* Wg2t = wbt + 9 * 16384;
    short* Ws2t = wbt + 10 * 16384;
    short* Wswt = wbt + 180224;
    short* Wlint = wbt + 212992;
    short* Wout2t = wbt + 245760;

    k_wtrans<<<6, 256, 0, stream>>>(a1Wg, a1Ws, Wq, Wk, Wv, Wga, wbt);
    k_main<<<1035, 512, 0, stream>>>(A_I, S_I, Wg1t, Ws1t, Wqt, Wkt, Wvt, Wgat,
                                     a1bg, bq, Z, ln0g, ln0b, Wb,
                                     Wa, Wop, ctWg, a2Wg, a2Ws, Wsw, Wlin, Wout2,
                                     Qb, Kb, Vb, Gb, BBt, wbt);
    k_attn_postf<<<512, 512, 0, stream>>>(Qb, Kb, Vb, Gb, BBt, maskK,
                                          S_I, A_I,
                                          Wat, Wopt, ctWgt, Wg2t, Ws2t,
                                          Wswt, Wlint, Wout2t,
                                          bop, ctbg, a2bg, out);
}

// Round 15
// 68.546 us; speedup vs baseline: 1.0674x; 1.0674x over previous
//
#include <hip/hip_runtime.h>

// Problem constants
#define DL 16384   // D*L tokens
#define LL 2048
#define NQB 64     // NQ
#define QBS 32     // QB
#define KBS 128    // KB

typedef __attribute__((ext_vector_type(8))) short short8;
typedef __attribute__((ext_vector_type(4))) short short4v;
typedef __attribute__((ext_vector_type(4))) float f32x4;

__device__ __forceinline__ float sigmoidf_(float x) { return 1.f / (1.f + expf(-x)); }

__device__ __forceinline__ short f2bf(float f) {
    union { float f; unsigned u; } v; v.f = f;
    unsigned r = (v.u + 0x7FFFu + ((v.u >> 16) & 1u)) >> 16;
    return (short)r;
}
__device__ __forceinline__ float bf2f(short h) {
    union { unsigned u; float f; } v; v.u = ((unsigned)(unsigned short)h) << 16;
    return v.f;
}
__device__ __forceinline__ unsigned packbf16(short a, short b) {
    return ((unsigned)(unsigned short)a) | (((unsigned)(unsigned short)b) << 16);
}

// fragment helpers (cl = lane&15, kg = lane>>4 must be in scope)
#define AFRAG(buf, stride, r0, kk) (*(const short8*)&(buf)[(size_t)((r0) + cl) * (stride) + (kk) * 32 + kg * 8])
#define WFRAG(Wt, K, n0, kk) (*(const short8*)((Wt) + (size_t)((n0) + cl) * (K) + (kk) * 32 + kg * 8))
#define MFMA(acc, a, b) acc = __builtin_amdgcn_mfma_f32_16x16x32_bf16(a, b, acc, 0, 0, 0)

// ---------------------------------------------------------------------------
// Kernel 0: weight transpose to bf16 [N][K] via LDS tile.  17 blocks.
// ---------------------------------------------------------------------------
__global__ __launch_bounds__(256) void k_wtrans(
    const float* __restrict__ W0, const float* __restrict__ W1, const float* __restrict__ W2,
    const float* __restrict__ W3, const float* __restrict__ W4, const float* __restrict__ W5,
    const float* __restrict__ W6, const float* __restrict__ W7, const float* __restrict__ W8,
    const float* __restrict__ W9, const float* __restrict__ W10,
    const float* __restrict__ Wsw, const float* __restrict__ Wlin, const float* __restrict__ Wout2,
    short* __restrict__ wout)
{
    __shared__ float sW[128 * 128];          // 64 KB
    const int b = blockIdx.x;
    const int tid = threadIdx.x;
    const float* srcs[14] = {W0,W1,W2,W3,W4,W5,W6,W7,W8,W9,W10,Wsw,Wlin,Wout2};
    const int sel[17]  = {0,1,2,3,4,5,6,7,8,9,10,11,11,12,12,13,13};
    const int soff[17] = {0,0,0,0,0,0,0,0,0,0,0, 0,128, 0,128, 0,16384};
    const int sN[17]   = {128,128,128,128,128,128,128,128,128,128,128, 256,256,256,256, 128,128};
    const int doff[17] = {0,16384,32768,49152,65536,81920,98304,114688,131072,147456,163840,
                          180224,196608, 212992,229376, 245760,245888};
    const int dK[17]   = {128,128,128,128,128,128,128,128,128,128,128, 128,128,128,128, 256,256};
    const float* src = srcs[sel[b]] + soff[b];
    const int srcN = sN[b];
    short* dst = wout + doff[b];
    const int dstK = dK[b];
    {   // coalesced load of 128x128 f32 tile
        const int r = tid >> 1, ch = (tid & 1) * 64;
        #pragma unroll
        for (int u = 0; u < 16; ++u) {
            float4 v = *(const float4*)(src + (size_t)r * srcN + ch + u * 4);
            *(float4*)&sW[r * 128 + ch + u * 4] = v;
        }
    }
    __syncthreads();
    {   // coalesced transposed bf16 write
        const int o = tid >> 1, kh = (tid & 1) * 64;
        #pragma unroll
        for (int u8 = 0; u8 < 8; ++u8) {
            short8 pk;
            #pragma unroll
            for (int e = 0; e < 8; ++e)
                pk[e] = f2bf(sW[(kh + u8 * 8 + e) * 128 + o]);
            *(short8*)(dst + (size_t)o * dstK + kh + u8 * 8) = pk;
        }
    }
}

// ---------------------------------------------------------------------------
// Kernel 1: adaLN1 + QKV+G projections (blocks 0..511, 32 tokens each)
//           AND pair-bias BBt[n][h][q:32][key:128] (blocks 512..1023).
// ---------------------------------------------------------------------------
__global__ __launch_bounds__(512) void k_main(
    const float* __restrict__ A_I, const float* __restrict__ S_I,
    const short* __restrict__ Wg1t, const short* __restrict__ Ws1t,
    const short* __restrict__ Wqt, const short* __restrict__ Wkt,
    const short* __restrict__ Wvt, const short* __restrict__ Wgat,
    const float* __restrict__ bg1, const float* __restrict__ bq,
    const float* __restrict__ Z, const float* __restrict__ g16, const float* __restrict__ b16,
    const float* __restrict__ Wb,
    short* __restrict__ Qo, short* __restrict__ Ko, short* __restrict__ Vo, short* __restrict__ Go,
    short* __restrict__ BBt)
{
    __shared__ short sAr[32 * 136];   // raw A bf16
    __shared__ short sSn[32 * 136];   // LN(S) bf16
    __shared__ short sAn[32 * 136];   // An bf16
    __shared__ float sMean[32], sRstd[32];
    __shared__ float sWb[64], sg[16], sb[16];
    __shared__ short sT[4 * 4 * 128]; // bias staging [h][il][j]
    const int bid = blockIdx.x;
    const int tid = threadIdx.x;
    const int lane = tid & 63;

    if (bid >= 512) {
        // ---------------- bias path: one 4-row slice of one n ----------------
        const int bb = bid - 512;        // 0..511
        const int n = bb >> 3;           // 0..63
        const int io = (bb & 7) * 4;     // 4-row slice
        if (tid < 64) sWb[tid] = Wb[tid];
        if (tid < 16) { sg[tid] = g16[tid]; sb[tid] = b16[tid]; }
        __syncthreads();
        {
            int il = tid >> 7, j = tid & 127;   // 512 threads = 4*128 pairs
            int i = io + il;
            int kr = n * 32 - 48 + j;
            int kc = min(max(kr, 0), LL - 1);
            const float4* z4 = (const float4*)(Z + ((long)(n * 32 + i) * LL + kc) * 16);
            float zv[16];
            #pragma unroll
            for (int w = 0; w < 4; ++w) {
                float4 v = z4[w];
                zv[w * 4 + 0] = v.x; zv[w * 4 + 1] = v.y; zv[w * 4 + 2] = v.z; zv[w * 4 + 3] = v.w;
            }
            float sm = 0.f, sq = 0.f;
            #pragma unroll
            for (int cp = 0; cp < 16; ++cp) { sm += zv[cp]; sq = fmaf(zv[cp], zv[cp], sq); }
            float m = sm * (1.f / 16.f);
            float rs = rsqrtf(sq * (1.f / 16.f) - m * m + 1e-5f);
            float b0 = 0.f, b1 = 0.f, b2 = 0.f, b3 = 0.f;
            #pragma unroll
            for (int cp = 0; cp < 16; ++cp) {
                float zn = (zv[cp] - m) * rs * sg[cp] + sb[cp];
                b0 = fmaf(zn, sWb[cp * 4 + 0], b0);
                b1 = fmaf(zn, sWb[cp * 4 + 1], b1);
                b2 = fmaf(zn, sWb[cp * 4 + 2], b2);
                b3 = fmaf(zn, sWb[cp * 4 + 3], b3);
            }
            sT[(0 * 4 + il) * 128 + j] = f2bf(b0);
            sT[(1 * 4 + il) * 128 + j] = f2bf(b1);
            sT[(2 * 4 + il) * 128 + j] = f2bf(b2);
            sT[(3 * 4 + il) * 128 + j] = f2bf(b3);
        }
        __syncthreads();
        {   // write BBt[n][h][q=io+il][key jb..jb+3]
            int hh = tid >> 7, rem = tid & 127;
            int il = rem >> 5, jb = (rem & 31) * 4;
            short4v pk = *(const short4v*)&sT[(hh * 4 + il) * 128 + jb];
            *(short4v*)(BBt + (((size_t)n * 4 + hh) * 32 + io + il) * 128 + jb) = pk;
        }
        return;
    }

    // ---------------- adaLN1 + QKVG path ----------------
    const long t0 = (long)bid * 32;
    {   // P0
        const int row = tid >> 4, seg = tid & 15;
        const float* ap = A_I + (t0 + row) * 128 + seg * 8;
        const float* sp = S_I + (t0 + row) * 128 + seg * 8;
        float av[8], sv[8];
        #pragma unroll
        for (int u = 0; u < 2; ++u) {
            float4 a4 = ((const float4*)ap)[u];
            float4 s4 = ((const float4*)sp)[u];
            av[4*u] = a4.x; av[4*u+1] = a4.y; av[4*u+2] = a4.z; av[4*u+3] = a4.w;
            sv[4*u] = s4.x; sv[4*u+1] = s4.y; sv[4*u+2] = s4.z; sv[4*u+3] = s4.w;
        }
        float am = 0.f, aq = 0.f, sm = 0.f, sq = 0.f;
        #pragma unroll
        for (int u = 0; u < 8; ++u) {
            am += av[u]; aq = fmaf(av[u], av[u], aq);
            sm += sv[u]; sq = fmaf(sv[u], sv[u], sq);
        }
        am += __shfl_xor(am, 1); am += __shfl_xor(am, 2); am += __shfl_xor(am, 4); am += __shfl_xor(am, 8);
        aq += __shfl_xor(aq, 1); aq += __shfl_xor(aq, 2); aq += __shfl_xor(aq, 4); aq += __shfl_xor(aq, 8);
        sm += __shfl_xor(sm, 1); sm += __shfl_xor(sm, 2); sm += __shfl_xor(sm, 4); sm += __shfl_xor(sm, 8);
        sq += __shfl_xor(sq, 1); sq += __shfl_xor(sq, 2); sq += __shfl_xor(sq, 4); sq += __shfl_xor(sq, 8);
        float amean = am * (1.f / 128.f);
        float arstd = rsqrtf(aq * (1.f / 128.f) - amean * amean + 1e-5f);
        float smean = sm * (1.f / 128.f);
        float srstd = rsqrtf(sq * (1.f / 128.f) - smean * smean + 1e-5f);
        if ((tid & 15) == 0) { sMean[row] = amean; sRstd[row] = arstd; }
        short8 pa, ps;
        #pragma unroll
        for (int e = 0; e < 8; ++e) {
            pa[e] = f2bf(av[e]);
            ps[e] = f2bf((sv[e] - smean) * srstd);
        }
        *(short8*)&sAr[row * 136 + seg * 8] = pa;
        *(short8*)&sSn[row * 136 + seg * 8] = ps;
    }
    __syncthreads();
    const int w = tid >> 6;
    const int n0 = w * 16;
    const int cl = lane & 15, kg = lane >> 4;
    {   // P1: An = sigmoid(sn@Wg1+bg1)*an + sn@Ws1  [swapped]
        short8 wg[4], wsf[4];
        #pragma unroll
        for (int kk = 0; kk < 4; ++kk) {
            wg[kk]  = WFRAG(Wg1t, 128, n0, kk);
            wsf[kk] = WFRAG(Ws1t, 128, n0, kk);
        }
        #pragma unroll
        for (int mt = 0; mt < 2; ++mt) {
            f32x4 ag = {0.f, 0.f, 0.f, 0.f}, as = {0.f, 0.f, 0.f, 0.f};
            #pragma unroll
            for (int kk = 0; kk < 4; ++kk) {
                short8 a = AFRAG(sSn, 136, mt * 16, kk);
                MFMA(ag, wg[kk], a);
                MFMA(as, wsf[kk], a);
            }
            const int tok = mt * 16 + cl;
            const int c0 = n0 + kg * 4;
            float4 bg4 = *(const float4*)&bg1[c0];
            float mean = sMean[tok], rstd = sRstd[tok];
            short4v ar4 = *(const short4v*)&sAr[tok * 136 + c0];
            short4v o;
            #pragma unroll
            for (int i = 0; i < 4; ++i) {
                float an = (bf2f(ar4[i]) - mean) * rstd;
                float An = sigmoidf_(ag[i] + ((const float*)&bg4)[i]) * an + as[i];
                o[i] = f2bf(An);
            }
            *(short4v*)&sAn[tok * 136 + c0] = o;
        }
    }
    __syncthreads();
    {   // P2: Q,K,V,G  [swapped, 8B stores]
        const float SCL = 0.17677669529663687f;  // 1/sqrt(32)
        short8 af[2][4];
        #pragma unroll
        for (int mt = 0; mt < 2; ++mt)
            #pragma unroll
            for (int kk = 0; kk < 4; ++kk)
                af[mt][kk] = AFRAG(sAn, 136, mt * 16, kk);
        const int c0 = n0 + kg * 4;
        float4 bq4 = *(const float4*)&bq[c0];
        #pragma unroll
        for (int m = 0; m < 4; ++m) {
            const short* Wt = (m == 0) ? Wqt : (m == 1) ? Wkt : (m == 2) ? Wvt : Wgat;
            short8 wf[4];
            #pragma unroll
            for (int kk = 0; kk < 4; ++kk) wf[kk] = WFRAG(Wt, 128, n0, kk);
            #pragma unroll
            for (int mt = 0; mt < 2; ++mt) {
                f32x4 acc = {0.f, 0.f, 0.f, 0.f};
                #pragma unroll
                for (int kk = 0; kk < 4; ++kk) MFMA(acc, wf[kk], af[mt][kk]);
                long t = t0 + mt * 16 + cl;
                short4v o;
                if (m == 0) {
                    #pragma unroll
                    for (int i = 0; i < 4; ++i) o[i] = f2bf((acc[i] + ((const float*)&bq4)[i]) * SCL);
                    *(short4v*)(Qo + t * 128 + c0) = o;
                } else if (m == 1) {
                    #pragma unroll
                    for (int i = 0; i < 4; ++i) o[i] = f2bf(acc[i]);
                    *(short4v*)(Ko + t * 128 + c0) = o;
                } else if (m == 2) {
                    #pragma unroll
                    for (int i = 0; i < 4; ++i) o[i] = f2bf(acc[i]);
                    *(short4v*)(Vo + t * 128 + c0) = o;
                } else {
                    #pragma unroll
                    for (int i = 0; i < 4; ++i) o[i] = f2bf(sigmoidf_(acc[i]));
                    *(short4v*)(Go + t * 128 + c0) = o;
                }
            }
        }
    }
}

// ---------------------------------------------------------------------------
// Kernel 2: FUSED attention + post, operand-swapped; A_I/S_I loads hoisted
// into registers before the PV barrier (T14-style overlap).
// ---------------------------------------------------------------------------
__global__ __launch_bounds__(512) void k_attn_postf(
    const short* __restrict__ Qg, const short* __restrict__ Kg, const short* __restrict__ Vg,
    const short* __restrict__ Gg, const short* __restrict__ BBt, const float* __restrict__ maskK,
    const float* __restrict__ S_I, const float* __restrict__ A_I,
    const short* __restrict__ Wat, const short* __restrict__ Wopt, const short* __restrict__ ctWgt,
    const short* __restrict__ Wg2t, const short* __restrict__ Ws2t,
    const short* __restrict__ Wswt, const short* __restrict__ Wlint, const short* __restrict__ Wout2t,
    const float* __restrict__ bop, const float* __restrict__ ctbg, const float* __restrict__ bg2,
    float* __restrict__ Out)
{
    __shared__ __align__(16) char smem[78336];
    short* sAF  = (short*)smem;              // [32][136] attn-out bf16 -> later an2
    short* vts  = (short*)(smem + 8704);     // [4][32][136] V^T   (attn phase)
    short* Pl   = (short*)(smem + 43520);    // [4][32][136] P     (attn phase)
    // post phase (overlays vts/Pl after barrier):
    short* sS   = (short*)(smem + 8704);     // [32][136] raw S bf16 -> sB
    short* sSn  = (short*)(smem + 17408);    // [32][136] LN(S) bf16
    float* sA   = (float*)(smem + 26112);    // [32][132] f32 A
    float* sMean = (float*)(smem + 43008);   // [32]
    float* sRstd = (float*)(smem + 43136);   // [32]
    short* sAn2 = sAF;
    short* sB   = (short*)(smem + 8704);     // [32][264] bf16 b

    const int n = blockIdx.x, d = blockIdx.y;
    const int tid = threadIdx.x;
    const int lane = tid & 63;
    const long tb = (long)d * LL;
    const long t0 = tb + n * 32;
    const int kbase = n * 32 - 48;
    const int cl = lane & 15, kg = lane >> 4;
    const int w = tid >> 6;
    const int h = w >> 1, amt = w & 1;       // attn wave = (head, q-half)

    {   // V^T staging: 512 threads; unit=(head,key-pair), half=16-channel half
        const int unit = tid >> 1, half = tid & 1;
        const int hh = unit >> 6, j0 = (unit & 63) * 2;
        int kc0 = min(max(kbase + j0, 0), LL - 1);
        int kc1 = min(max(kbase + j0 + 1, 0), LL - 1);
        const short8* p0 = (const short8*)(Vg + (tb + kc0) * 128 + hh * 32 + half * 16);
        const short8* p1 = (const short8*)(Vg + (tb + kc1) * 128 + hh * 32 + half * 16);
        short8 e0 = p0[0], e1 = p0[1];
        short8 o0 = p1[0], o1 = p1[1];
        short* vh = vts + hh * 4352;
        #pragma unroll
        for (int e = 0; e < 8; ++e)
            *(unsigned*)&vh[(half * 16 + e) * 136 + j0] = packbf16(e0[e], o0[e]);
        #pragma unroll
        for (int e = 0; e < 8; ++e)
            *(unsigned*)&vh[(half * 16 + 8 + e) * 136 + j0] = packbf16(e1[e], o1[e]);
    }

    float sc[8][4];
    {   // swapped QK^T: lane -> token = amt*16+cl, keys nt*16+kg*4+i
        short8 qf = *(const short8*)(Qg + (t0 + amt * 16 + cl) * 128 + h * 32 + kg * 8);
        #pragma unroll
        for (int nt = 0; nt < 8; ++nt) {
            int kc = min(max(kbase + nt * 16 + cl, 0), LL - 1);
            short8 kf = *(const short8*)(Kg + (tb + kc) * 128 + h * 32 + kg * 8);
            f32x4 s = {0.f, 0.f, 0.f, 0.f};
            MFMA(s, kf, qf);       // A=K rows (m=key), B=Q rows (n=token)
            float4 mk4 = *(const float4*)(maskK + n * 128 + nt * 16 + kg * 4);
            short4v bfr = *(const short4v*)(BBt + (((size_t)n * 4 + h) * 32 + amt * 16 + cl) * 128 + nt * 16 + kg * 4);
            #pragma unroll
            for (int i = 0; i < 4; ++i)
                sc[nt][i] = s[i] + bf2f(bfr[i]) - ((const float*)&mk4)[i] * 1e9f;
        }
    }
    {   // softmax per token (lane holds 32 keys; reduce across 4 kg groups)
        float mx = sc[0][0];
        #pragma unroll
        for (int nt = 0; nt < 8; ++nt)
            #pragma unroll
            for (int i = 0; i < 4; ++i) mx = fmaxf(mx, sc[nt][i]);
        mx = fmaxf(mx, __shfl_xor(mx, 16));
        mx = fmaxf(mx, __shfl_xor(mx, 32));
        float sm = 0.f;
        #pragma unroll
        for (int nt = 0; nt < 8; ++nt)
            #pragma unroll
            for (int i = 0; i < 4; ++i) {
                float p = __expf(sc[nt][i] - mx);
                sc[nt][i] = p; sm += p;
            }
        sm += __shfl_xor(sm, 16);
        sm += __shfl_xor(sm, 32);
        float inv = 1.f / sm;
        short* PH = Pl + h * 4352;
        const int tok = amt * 16 + cl;
        #pragma unroll
        for (int nt = 0; nt < 8; ++nt) {
            short4v p4;
            #pragma unroll
            for (int i = 0; i < 4; ++i) p4[i] = f2bf(sc[nt][i] * inv);
            *(short4v*)&PH[tok * 136 + nt * 16 + kg * 4] = p4;
        }
    }

    // T14: issue next-phase A_I/S_I global loads NOW (registers), so the HBM
    // latency hides under the PV MFMA phase that follows the barrier.
    const int prow = tid >> 4, pseg = tid & 15;
    float pav[8], psv[8];
    {
        const float* apI = A_I + (t0 + prow) * 128 + pseg * 8;
        const float* spI = S_I + (t0 + prow) * 128 + pseg * 8;
        #pragma unroll
        for (int u = 0; u < 2; ++u) {
            float4 a4 = ((const float4*)apI)[u];
            float4 s4 = ((const float4*)spI)[u];
            pav[4*u] = a4.x; pav[4*u+1] = a4.y; pav[4*u+2] = a4.z; pav[4*u+3] = a4.w;
            psv[4*u] = s4.x; psv[4*u+1] = s4.y; psv[4*u+2] = s4.z; psv[4*u+3] = s4.w;
        }
    }

    __syncthreads();   // V^T + P complete
    {   // PV + G-gate -> sAF (LDS), swapped: C col=token, rows=channels
        short* PH = Pl + h * 4352;
        short* vh = vts + h * 4352;
        const int tok = amt * 16 + cl;
        short8 pfr[4];
        #pragma unroll
        for (int kk = 0; kk < 4; ++kk)
            pfr[kk] = *(const short8*)&PH[tok * 136 + kk * 32 + kg * 8];
        #pragma unroll
        for (int ct = 0; ct < 2; ++ct) {
            f32x4 acc = {0.f, 0.f, 0.f, 0.f};
            #pragma unroll
            for (int kk = 0; kk < 4; ++kk) {
                short8 a = *(const short8*)&vh[(ct * 16 + cl) * 136 + kk * 32 + kg * 8];
                MFMA(acc, a, pfr[kk]);
            }
            const int c0 = h * 32 + ct * 16 + kg * 4;
            short4v g4 = *(const short4v*)(Gg + (t0 + tok) * 128 + c0);
            short4v o4;
            #pragma unroll
            for (int i = 0; i < 4; ++i) o4[i] = f2bf(bf2f(g4[i]) * acc[i]);
            *(short4v*)&sAF[tok * 136 + c0] = o4;
        }
    }
    __syncthreads();   // attn done; vts/Pl now dead

    // ---------------- post phase ----------------
    {   // P0: LN stats from pre-loaded registers; write sA/sS/sSn
        #pragma unroll
        for (int u = 0; u < 2; ++u)
            *(float4*)&sA[prow * 132 + pseg * 8 + u * 4] = *(const float4*)&pav[u * 4];
        float sm = 0.f, sq = 0.f;
        #pragma unroll
        for (int u = 0; u < 8; ++u) { sm += psv[u]; sq = fmaf(psv[u], psv[u], sq); }
        sm += __shfl_xor(sm, 1); sm += __shfl_xor(sm, 2); sm += __shfl_xor(sm, 4); sm += __shfl_xor(sm, 8);
        sq += __shfl_xor(sq, 1); sq += __shfl_xor(sq, 2); sq += __shfl_xor(sq, 4); sq += __shfl_xor(sq, 8);
        float smean = sm * (1.f / 128.f);
        float srstd = rsqrtf(sq * (1.f / 128.f) - smean * smean + 1e-5f);
        short8 pr, pn;
        #pragma unroll
        for (int e = 0; e < 8; ++e) {
            float s = psv[e];
            pr[e] = f2bf(s);
            pn[e] = f2bf((s - smean) * srstd);
        }
        *(short8*)&sS [prow * 136 + pseg * 8] = pr;
        *(short8*)&sSn[prow * 136 + pseg * 8] = pn;
    }
    __syncthreads();
    const int n0 = w * 16;
    const int c0 = n0 + kg * 4;
    float g2s[8];

    {   // P2: A = A_I + sigmoid(S@Wop+bop)*(AF@Wa);  g2 = sigmoid(S@ctWg+ctbg)
        short8 wA[4], wO[4], wG[4];
        #pragma unroll
        for (int kk = 0; kk < 4; ++kk) {
            wA[kk] = WFRAG(Wat, 128, n0, kk);
            wO[kk] = WFRAG(Wopt, 128, n0, kk);
            wG[kk] = WFRAG(ctWgt, 128, n0, kk);
        }
        float4 bop4 = *(const float4*)&bop[c0];
        float4 ct4  = *(const float4*)&ctbg[c0];
        #pragma unroll
        for (int rt = 0; rt < 2; ++rt) {
            f32x4 aA = {0.f,0.f,0.f,0.f}, aO = {0.f,0.f,0.f,0.f}, aG = {0.f,0.f,0.f,0.f};
            #pragma unroll
            for (int kk = 0; kk < 4; ++kk) {
                short8 af = AFRAG(sAF, 136, rt * 16, kk);
                short8 sf = AFRAG(sS, 136, rt * 16, kk);
                MFMA(aA, wA[kk], af);
                MFMA(aO, wO[kk], sf);
                MFMA(aG, wG[kk], sf);
            }
            const int tok = rt * 16 + cl;
            float4 Av = *(const float4*)&sA[tok * 132 + c0];
            float4 outv;
            #pragma unroll
            for (int i = 0; i < 4; ++i) {
                ((float*)&outv)[i] = ((const float*)&Av)[i]
                    + sigmoidf_(aO[i] + ((const float*)&bop4)[i]) * aA[i];
                g2s[rt * 4 + i] = sigmoidf_(aG[i] + ((const float*)&ct4)[i]);
            }
            *(float4*)&sA[tok * 132 + c0] = outv;
        }
    }
    __syncthreads();
    {   // P3: LN stats of A rows
        float m = 0.f, q = 0.f;
        #pragma unroll
        for (int u = 0; u < 2; ++u) {
            float4 v = *(const float4*)&sA[prow * 132 + pseg * 8 + u * 4];
            m += v.x + v.y + v.z + v.w;
            q = fmaf(v.x, v.x, q); q = fmaf(v.y, v.y, q);
            q = fmaf(v.z, v.z, q); q = fmaf(v.w, v.w, q);
        }
        m += __shfl_xor(m, 1); m += __shfl_xor(m, 2); m += __shfl_xor(m, 4); m += __shfl_xor(m, 8);
        q += __shfl_xor(q, 1); q += __shfl_xor(q, 2); q += __shfl_xor(q, 4); q += __shfl_xor(q, 8);
        float mean = m * (1.f / 128.f);
        float rstd = rsqrtf(q * (1.f / 128.f) - mean * mean + 1e-5f);
        if ((tid & 15) == 0) { sMean[prow] = mean; sRstd[prow] = rstd; }
    }
    __syncthreads();
    {   // P4: an2 = sigmoid(sn@Wg2+bg2)*LN(A) + sn@Ws2  (writes sAn2 = sAF)
        short8 wg2[4], ws2[4];
        #pragma unroll
        for (int kk = 0; kk < 4; ++kk) {
            wg2[kk] = WFRAG(Wg2t, 128, n0, kk);
            ws2[kk] = WFRAG(Ws2t, 128, n0, kk);
        }
        float4 bg24 = *(const float4*)&bg2[c0];
        #pragma unroll
        for (int rt = 0; rt < 2; ++rt) {
            f32x4 ag = {0.f,0.f,0.f,0.f}, as = {0.f,0.f,0.f,0.f};
            #pragma unroll
            for (int kk = 0; kk < 4; ++kk) {
                short8 a = AFRAG(sSn, 136, rt * 16, kk);
                MFMA(ag, wg2[kk], a);
                MFMA(as, ws2[kk], a);
            }
            const int tok = rt * 16 + cl;
            float mean = sMean[tok], rstd = sRstd[tok];
            float4 Av = *(const float4*)&sA[tok * 132 + c0];
            short4v o;
            #pragma unroll
            for (int i = 0; i < 4; ++i) {
                float lnA = (((const float*)&Av)[i] - mean) * rstd;
                o[i] = f2bf(sigmoidf_(ag[i] + ((const float*)&bg24)[i]) * lnA + as[i]);
            }
            *(short4v*)&sAn2[tok * 136 + c0] = o;
        }
    }
    __syncthreads();
    {   // P5: b = silu(an2@Wsw) * (an2@Wlin)  (writes sB over sS/sSn)
        short8 a2f[2][4];
        #pragma unroll
        for (int rt = 0; rt < 2; ++rt)
            #pragma unroll
            for (int kk = 0; kk < 4; ++kk)
                a2f[rt][kk] = AFRAG(sAn2, 136, rt * 16, kk);
        #pragma unroll
        for (int j = 0; j < 2; ++j) {
            const int n0b = w * 32 + j * 16;
            short8 ww[4], wl[4];
            #pragma unroll
            for (int kk = 0; kk < 4; ++kk) {
                ww[kk] = WFRAG(Wswt, 128, n0b, kk);
                wl[kk] = WFRAG(Wlint, 128, n0b, kk);
            }
            #pragma unroll
            for (int rt = 0; rt < 2; ++rt) {
                f32x4 aw = {0.f,0.f,0.f,0.f}, al = {0.f,0.f,0.f,0.f};
                #pragma unroll
                for (int kk = 0; kk < 4; ++kk) {
                    MFMA(aw, ww[kk], a2f[rt][kk]);
                    MFMA(al, wl[kk], a2f[rt][kk]);
                }
                const int tok = rt * 16 + cl;
                short4v o;
                #pragma unroll
                for (int i = 0; i < 4; ++i) {
                    float x = aw[i];
                    o[i] = f2bf((x / (1.f + expf(-x))) * al[i]);
                }
                *(short4v*)&sB[tok * 264 + n0b + kg * 4] = o;
            }
        }
    }
    __syncthreads();
    {   // P6: out = A + g2 * (b @ Wout2)  [float4 stores]
        short8 wo[8];
        #pragma unroll
        for (int kk = 0; kk < 8; ++kk) wo[kk] = WFRAG(Wout2t, 256, n0, kk);
        #pragma unroll
        for (int rt = 0; rt < 2; ++rt) {
            f32x4 acc = {0.f,0.f,0.f,0.f};
            #pragma unroll
            for (int kk = 0; kk < 8; ++kk) {
                short8 a = AFRAG(sB, 264, rt * 16, kk);
                MFMA(acc, wo[kk], a);
            }
            const int tok = rt * 16 + cl;
            float4 Av = *(const float4*)&sA[tok * 132 + c0];
            float4 outv;
            #pragma unroll
            for (int i = 0; i < 4; ++i)
                ((float*)&outv)[i] = ((const float*)&Av)[i] + g2s[rt * 4 + i] * acc[i];
            *(float4*)(Out + (t0 + tok) * 128 + c0) = outv;
        }
    }
}

// ---------------------------------------------------------------------------
extern "C" void kernel_launch(void* const* d_in, const int* in_sizes, int n_in,
                              void* d_out, int out_size, void* d_ws, size_t ws_size,
                              hipStream_t stream)
{
    const float* A_I  = (const float*)d_in[0];
    const float* S_I  = (const float*)d_in[1];
    const float* Z    = (const float*)d_in[2];
    const float* maskK = (const float*)d_in[6];
    const float* a1Wg = (const float*)d_in[7];
    const float* a1bg = (const float*)d_in[8];
    const float* a1Ws = (const float*)d_in[9];
    const float* Wq   = (const float*)d_in[10];
    const float* bq   = (const float*)d_in[11];
    const float* Wk   = (const float*)d_in[12];
    const float* Wv   = (const float*)d_in[13];
    const float* ln0g = (const float*)d_in[14];
    const float* ln0b = (const float*)d_in[15];
    const float* Wb   = (const float*)d_in[16];
    const float* Wga  = (const float*)d_in[17];
    const float* Wa   = (const float*)d_in[18];
    const float* Wop  = (const float*)d_in[19];
    const float* bop  = (const float*)d_in[20];
    const float* a2Wg = (const float*)d_in[21];
    const float* a2bg = (const float*)d_in[22];
    const float* a2Ws = (const float*)d_in[23];
    const float* Wsw  = (const float*)d_in[24];
    const float* Wlin = (const float*)d_in[25];
    const float* ctWg = (const float*)d_in[26];
    const float* ctbg = (const float*)d_in[27];
    const float* Wout2 = (const float*)d_in[28];
    float* out = (float*)d_out;

    const size_t NTC = (size_t)DL * 128;   // 2,097,152 elems per (D,L,C) tensor
    short* Qb = (short*)d_ws;
    short* Kb = Qb + NTC;
    short* Vb = Kb + NTC;
    short* Gb = Vb + NTC;
    short* BBt = Gb + NTC;                 // [64][4][32][128] bf16 = 2 MB
    short* wbt = BBt + (size_t)NQB * 4 * 32 * 128;

    short* Wg1t = wbt + 0 * 16384;
    short* Ws1t = wbt + 1 * 16384;
    short* Wqt  = wbt + 2 * 16384;
    short* Wkt  = wbt + 3 * 16384;
    short* Wvt  = wbt + 4 * 16384;
    short* Wgat = wbt + 5 * 16384;
    short* Wat  = wbt + 6 * 16384;
    short* Wopt = wbt + 7 * 16384;
    short* ctWgt = wbt + 8 * 16384;
    short* Wg2t = wbt + 9 * 16384;
    short* Ws2t = wbt + 10 * 16384;
    short* Wswt = wbt + 180224;
    short* Wlint = wbt + 212992;
    short* Wout2t = wbt + 245760;

    k_wtrans<<<17, 256, 0, stream>>>(a1Wg, a1Ws, Wq, Wk, Wv, Wga, Wa, Wop, ctWg,
                                     a2Wg, a2Ws, Wsw, Wlin, Wout2, wbt);
    k_main<<<1024, 512, 0, stream>>>(A_I, S_I, Wg1t, Ws1t, Wqt, Wkt, Wvt, Wgat,
                                     a1bg, bq, Z, ln0g, ln0b, Wb,
                                     Qb, Kb, Vb, Gb, BBt);
    k_attn_postf<<<dim3(NQB, 8), 512, 0, stream>>>(Qb, Kb, Vb, Gb, BBt, maskK,
                                                   S_I, A_I,
                                                   Wat, Wopt, ctWgt, Wg2t, Ws2t,
                                                   Wswt, Wlint, Wout2t,
                                                   bop, ctbg, a2bg, out);
}